// Round 1
// baseline (198.372 us; speedup 1.0000x reference)
//
#include <hip/hip_runtime.h>

#define N_      32
#define CIN     128
#define HW_     56
#define COUT    256
#define HP      58                    // padded spatial
#define SP_     (HW_*HW_)             // 3136
#define M_      (N_*SP_)              // 100352
#define XP_BYTES (N_*HP*HP*CIN)       // 13,778,944
#define WP_BYTES (9*COUT*CIN)         // 294,912

typedef int int4v  __attribute__((ext_vector_type(4)));
typedef int int16v __attribute__((ext_vector_type(16)));

// ---------------- repack x: int32 NCHW -> int8 NHWC, spatially padded ----------------
__global__ __launch_bounds__(256) void repack_x(const int* __restrict__ x32,
                                                char* __restrict__ xp) {
    __shared__ char s8[CIN * HW_];                    // 7168 B
    int b = blockIdx.x;
    int n = b / HW_;
    int h = b - n * HW_;
    const int* src = x32 + (n * CIN) * SP_ + h * HW_; // + c*3136 + w
    for (int i = threadIdx.x; i < CIN * HW_; i += 256) {
        int c = i / HW_, w = i - c * HW_;
        s8[i] = (char)src[c * SP_ + w];
    }
    __syncthreads();
    // dst pixel (n, h+1, 1), c contiguous; write packed dwords
    int* dst = (int*)(xp + ((size_t)((n * HP + h + 1) * HP + 1)) * CIN);
    for (int i = threadIdx.x; i < HW_ * (CIN / 4); i += 256) {
        int w = i >> 5, c4 = i & 31;
        int v0 = (unsigned char)s8[(c4 * 4 + 0) * HW_ + w];
        int v1 = (unsigned char)s8[(c4 * 4 + 1) * HW_ + w];
        int v2 = (unsigned char)s8[(c4 * 4 + 2) * HW_ + w];
        int v3 = (unsigned char)s8[(c4 * 4 + 3) * HW_ + w];
        dst[w * (CIN / 4) + c4] = v0 | (v1 << 8) | (v2 << 16) | (v3 << 24);
    }
}

// ---------------- repack w: int32 [co][c][kh][kw] -> int8 [tap][co][c] ----------------
__global__ __launch_bounds__(256) void repack_w(const int* __restrict__ w32,
                                                char* __restrict__ wp) {
    int i = blockIdx.x * 256 + threadIdx.x;   // dword index < 73728
    int tap = i >> 13;                        // 256*128/4 = 8192 dwords per tap
    int r   = i & 8191;
    int co  = r >> 5;
    int c4  = r & 31;
    const int* s = w32 + (co * CIN + c4 * 4) * 9 + tap;
    int v0 = s[0]  & 0xff;
    int v1 = s[9]  & 0xff;
    int v2 = s[18] & 0xff;
    int v3 = s[27] & 0xff;
    ((int*)wp)[i] = v0 | (v1 << 8) | (v2 << 16) | (v3 << 24);
}

// ---------------- main: implicit GEMM with mfma_i32_32x32x32_i8 ----------------
// grid (M/128, COUT/64), 256 threads = 4 waves; wave w owns rows m_base..m_base+31,
// computes 32(M) x 64(Cout) via two 32x32 accumulators.
__global__ __launch_bounds__(256) void conv_mfma(const char* __restrict__ xp,
                                                 const char* __restrict__ wp,
                                                 const int*  __restrict__ bias,
                                                 const float* __restrict__ wsc,
                                                 int* __restrict__ out) {
    int tid  = threadIdx.x;
    int wave = tid >> 6, lane = tid & 63;
    int l31 = lane & 31, lh = lane >> 5;

    int m_base = blockIdx.x * 128 + wave * 32;
    int row = m_base + l31;
    int n  = row / SP_;
    int sp = row - n * SP_;
    int ho = sp / HW_;
    int wo = sp - ho * HW_;

    const char* aptr = xp + ((size_t)((n * HP + ho) * HP + wo) << 7) + (lh << 4);
    int co0 = (blockIdx.y << 6) + l31;
    const char* bptr = wp + (co0 << 7) + (lh << 4);

    int16v acc0 = {0};
    int16v acc1 = {0};

#pragma unroll
    for (int kh = 0; kh < 3; ++kh) {
#pragma unroll
        for (int kw = 0; kw < 3; ++kw) {
            const char* at = aptr + (kh * HP + kw) * CIN;
            const char* bt = bptr + (kh * 3 + kw) * (COUT * CIN);
#pragma unroll
            for (int kc = 0; kc < 4; ++kc) {
                int4v a  = *(const int4v*)(at + kc * 32);
                int4v b0 = *(const int4v*)(bt + kc * 32);
                int4v b1 = *(const int4v*)(bt + 32 * CIN + kc * 32);
                acc0 = __builtin_amdgcn_mfma_i32_32x32x32_i8(a, b0, acc0, 0, 0, 0);
                acc1 = __builtin_amdgcn_mfma_i32_32x32x32_i8(a, b1, acc1, 0, 0, 0);
            }
        }
    }

    // epilogue: C/D layout col = lane&31, row = (r&3) + 8*(r>>2) + 4*(lane>>5)
    int nu  = m_base / SP_;
    int sp0 = m_base - nu * SP_;       // multiple of 32, rows stay in one n
    int hl4 = lh << 2;

#pragma unroll
    for (int j = 0; j < 2; ++j) {
        int co = (blockIdx.y << 6) + j * 32 + l31;
        float s = (0.02f * wsc[co]) / 0.1f;
        int bs = bias[co];
        int* ob = out + ((size_t)(nu * COUT + co)) * SP_ + sp0 + hl4;
        const int16v& A = j ? acc1 : acc0;
#pragma unroll
        for (int r = 0; r < 16; ++r) {
            int roff = (r & 3) + ((r >> 2) << 3);
            float v = (float)(A[r] + bs) * s;
            int q = (int)rintf(v);
            q = q < -128 ? -128 : (q > 127 ? 127 : q);
            ob[roff] = q;
        }
    }
}

extern "C" void kernel_launch(void* const* d_in, const int* in_sizes, int n_in,
                              void* d_out, int out_size, void* d_ws, size_t ws_size,
                              hipStream_t stream) {
    const int*   x32  = (const int*)d_in[0];
    const int*   w32  = (const int*)d_in[1];
    const int*   bias = (const int*)d_in[2];
    const float* wsc  = (const float*)d_in[3];

    char* xp = (char*)d_ws;
    char* wp = xp + XP_BYTES;

    hipMemsetAsync(xp, 0, XP_BYTES, stream);                       // zero halo (zp = 0)
    repack_x<<<dim3(N_ * HW_), 256, 0, stream>>>(x32, xp);
    repack_w<<<dim3(WP_BYTES / 4 / 256), 256, 0, stream>>>(w32, wp);
    conv_mfma<<<dim3(M_ / 128, COUT / 64), 256, 0, stream>>>(xp, wp, bias, wsc,
                                                             (int*)d_out);
}

// Round 3
// 115.692 us; speedup vs baseline: 1.7147x; 1.7147x over previous
//
#include <hip/hip_runtime.h>

#define N_      32
#define CIN     128
#define HW_     56
#define COUT    256
#define HP      58                    // padded spatial
#define SP_     (HW_*HW_)             // 3136
#define M_      (N_*SP_)              // 100352
#define XP_BYTES (N_*HP*HP*CIN)       // 13,778,944
#define WP_BYTES (9*COUT*CIN)         // 294,912

typedef int int4v  __attribute__((ext_vector_type(4)));
typedef int int16v __attribute__((ext_vector_type(16)));

// ---------------- repack x: int32 NCHW -> int8 NHWC, spatially padded ----------------
__global__ __launch_bounds__(256) void repack_x(const int* __restrict__ x32,
                                                char* __restrict__ xp) {
    __shared__ char s8[CIN * HW_];                    // 7168 B
    int b = blockIdx.x;
    int n = b / HW_;
    int h = b - n * HW_;
    const int* src = x32 + (n * CIN) * SP_ + h * HW_; // + c*3136 + w
    for (int i = threadIdx.x; i < CIN * HW_; i += 256) {
        int c = i / HW_, w = i - c * HW_;
        s8[i] = (char)src[c * SP_ + w];
    }
    __syncthreads();
    int* dst = (int*)(xp + ((size_t)((n * HP + h + 1) * HP + 1)) * CIN);
    for (int i = threadIdx.x; i < HW_ * (CIN / 4); i += 256) {
        int w = i >> 5, c4 = i & 31;
        int v0 = (unsigned char)s8[(c4 * 4 + 0) * HW_ + w];
        int v1 = (unsigned char)s8[(c4 * 4 + 1) * HW_ + w];
        int v2 = (unsigned char)s8[(c4 * 4 + 2) * HW_ + w];
        int v3 = (unsigned char)s8[(c4 * 4 + 3) * HW_ + w];
        dst[w * (CIN / 4) + c4] = v0 | (v1 << 8) | (v2 << 16) | (v3 << 24);
    }
}

// ---------------- repack w: int32 [co][c][kh][kw] -> int8 [tap][co][c] ----------------
__global__ __launch_bounds__(256) void repack_w(const int* __restrict__ w32,
                                                char* __restrict__ wp) {
    int i = blockIdx.x * 256 + threadIdx.x;   // dword index < 73728
    int tap = i >> 13;
    int r   = i & 8191;
    int co  = r >> 5;
    int c4  = r & 31;
    const int* s = w32 + (co * CIN + c4 * 4) * 9 + tap;
    int v0 = s[0]  & 0xff;
    int v1 = s[9]  & 0xff;
    int v2 = s[18] & 0xff;
    int v3 = s[27] & 0xff;
    ((int*)wp)[i] = v0 | (v1 << 8) | (v2 << 16) | (v3 << 24);
}

// ---------------- main: implicit GEMM, BM=256 BN=64, wave tile 64x64 ----------------
// grid (M/256, COUT/64), 4 waves; B (weights) staged in LDS (6+3 taps, XOR-swizzled),
// A from global (L1-cached, 9x tap reuse).
__global__ __launch_bounds__(256, 3) void conv_mfma(const char* __restrict__ xp,
                                                    const char* __restrict__ wp,
                                                    const int*  __restrict__ bias,
                                                    const float* __restrict__ wsc,
                                                    int* __restrict__ out) {
    __shared__ char Bs[6 * 8192];                 // 48 KiB
    const int tid  = threadIdx.x;
    const int wave = tid >> 6, lane = tid & 63;
    const int l31 = lane & 31, lh = lane >> 5;
    const int m_base = blockIdx.x << 8;
    const int co0    = blockIdx.y << 6;

    const char* aptr[2];
    int tb[2];
#pragma unroll
    for (int mf = 0; mf < 2; ++mf) {
        tb[mf] = m_base + wave * 64 + mf * 32;    // multiple of 32; 3136%32==0 -> same n
        int row = tb[mf] + l31;
        int n  = row / SP_;
        int sp = row - n * SP_;
        int ho = sp / HW_;
        int wo = sp - ho * HW_;
        aptr[mf] = xp + (((size_t)(n * HP + ho) * HP + wo) << 7) + (lh << 4);
    }

    const char* wpb = wp + co0 * CIN;

    int16v acc[2][2] = {};

    // stage nt taps (t0..t0+nt-1) into slabs starting at Bs[0]; linear dest,
    // inverse-swizzled per-lane source (swz is an involution on byte bits 4-6)
    auto stageB = [&](int t0, int nt) {
        for (int i = wave; i < nt * 8; i += 4) {
            int p = (i << 10) + (lane << 4);              // linear LDS byte
            int q = p ^ (((p >> 7) & 7) << 4);            // swizzled source offset
            const char* src = wpb + (t0 + (p >> 13)) * (COUT * CIN) + (q & 8191);
            __builtin_amdgcn_global_load_lds(
                (const __attribute__((address_space(1))) void*)src,
                (__attribute__((address_space(3))) void*)&Bs[i << 10], 16, 0, 0);
        }
    };

    auto computeT = [&](int t0, int nt, int slab0) {
#pragma unroll
        for (int t = 0; t < nt; ++t) {
            int tap = t0 + t;
            int kh = tap / 3, kw = tap - kh * 3;
            int aoff  = (kh * HP + kw) << 7;
            int bbase = (slab0 + t) << 13;
            int sw = (l31 & 7) << 4;
#pragma unroll
            for (int kc = 0; kc < 4; ++kc) {
                int4v a0 = *(const int4v*)(aptr[0] + aoff + kc * 32);
                int4v a1 = *(const int4v*)(aptr[1] + aoff + kc * 32);
                int koff = kc * 32 + (lh << 4);
                int p0 = (bbase + (l31 << 7) + koff) ^ sw;
                int p1 = (bbase + ((l31 + 32) << 7) + koff) ^ sw;
                int4v b0 = *(const int4v*)&Bs[p0];
                int4v b1 = *(const int4v*)&Bs[p1];
                acc[0][0] = __builtin_amdgcn_mfma_i32_32x32x32_i8(a0, b0, acc[0][0], 0, 0, 0);
                acc[1][0] = __builtin_amdgcn_mfma_i32_32x32x32_i8(a1, b0, acc[1][0], 0, 0, 0);
                acc[0][1] = __builtin_amdgcn_mfma_i32_32x32x32_i8(a0, b1, acc[0][1], 0, 0, 0);
                acc[1][1] = __builtin_amdgcn_mfma_i32_32x32x32_i8(a1, b1, acc[1][1], 0, 0, 0);
            }
        }
    };

    stageB(0, 6);                 // taps 0-5 -> slabs 0-5
    __syncthreads();
    computeT(0, 3, 0);            // taps 0-2
    __syncthreads();              // everyone done reading slabs 0-2
    stageB(6, 3);                 // taps 6-8 -> slabs 0-2 (async, overlaps next compute)
    computeT(3, 3, 3);            // taps 3-5
    __syncthreads();              // drains vmcnt -> stage complete
    computeT(6, 3, 0);            // taps 6-8

    // epilogue: C/D row = (r&3) + 8*(r>>2) + 4*lh; rows r..r+3 of a group are
    // consecutive sp -> pack 4 int32 into one dwordx4 store
#pragma unroll
    for (int mf = 0; mf < 2; ++mf) {
        int nu  = tb[mf] / SP_;
        int sp0 = tb[mf] - nu * SP_;
#pragma unroll
        for (int nf = 0; nf < 2; ++nf) {
            int co = co0 + nf * 32 + l31;
            float s = (0.02f * wsc[co]) / 0.1f;
            int bs = bias[co];
            int* ob = out + ((size_t)(nu * COUT + co)) * SP_ + sp0 + (lh << 2);
#pragma unroll
            for (int g = 0; g < 4; ++g) {
                int4v qv;
#pragma unroll
                for (int r = 0; r < 4; ++r) {
                    float v = (float)(acc[mf][nf][g * 4 + r] + bs) * s;
                    int q = (int)rintf(v);
                    qv[r] = q < -128 ? -128 : (q > 127 ? 127 : q);
                }
                *(int4v*)(ob + g * 8) = qv;
            }
        }
    }
}

extern "C" void kernel_launch(void* const* d_in, const int* in_sizes, int n_in,
                              void* d_out, int out_size, void* d_ws, size_t ws_size,
                              hipStream_t stream) {
    const int*   x32  = (const int*)d_in[0];
    const int*   w32  = (const int*)d_in[1];
    const int*   bias = (const int*)d_in[2];
    const float* wsc  = (const float*)d_in[3];

    char* xp = (char*)d_ws;
    char* wp = xp + XP_BYTES;

    hipMemsetAsync(xp, 0, XP_BYTES, stream);                       // zero halo (zp = 0)
    repack_x<<<dim3(N_ * HW_), 256, 0, stream>>>(x32, xp);
    repack_w<<<dim3(WP_BYTES / 4 / 256), 256, 0, stream>>>(w32, wp);
    conv_mfma<<<dim3(M_ / 256, COUT / 64), 256, 0, stream>>>(xp, wp, bias, wsc,
                                                             (int*)d_out);
}

// Round 4
// 111.401 us; speedup vs baseline: 1.7807x; 1.0385x over previous
//
#include <hip/hip_runtime.h>

#define N_      32
#define CIN     128
#define HW_     56
#define COUT    256
#define HP      58                    // padded spatial
#define SP_     (HW_*HW_)             // 3136
#define M_      (N_*SP_)              // 100352
#define XP_BYTES (N_*HP*HP*CIN)       // 13,778,944
#define WP_BYTES (9*COUT*CIN)         // 294,912

typedef int int4v  __attribute__((ext_vector_type(4)));
typedef int int16v __attribute__((ext_vector_type(16)));

// ---------------- repack x: int32 NCHW -> int8 NHWC, spatially padded ----------------
__global__ __launch_bounds__(256) void repack_x(const int* __restrict__ x32,
                                                char* __restrict__ xp) {
    __shared__ char s8[CIN * HW_];                    // 7168 B
    int b = blockIdx.x;
    int n = b / HW_;
    int h = b - n * HW_;
    const int* src = x32 + (n * CIN) * SP_ + h * HW_; // + c*3136 + w
    for (int i = threadIdx.x; i < CIN * HW_; i += 256) {
        int c = i / HW_, w = i - c * HW_;
        s8[i] = (char)src[c * SP_ + w];
    }
    __syncthreads();
    int* dst = (int*)(xp + ((size_t)((n * HP + h + 1) * HP + 1)) * CIN);
    for (int i = threadIdx.x; i < HW_ * (CIN / 4); i += 256) {
        int w = i >> 5, c4 = i & 31;
        int v0 = (unsigned char)s8[(c4 * 4 + 0) * HW_ + w];
        int v1 = (unsigned char)s8[(c4 * 4 + 1) * HW_ + w];
        int v2 = (unsigned char)s8[(c4 * 4 + 2) * HW_ + w];
        int v3 = (unsigned char)s8[(c4 * 4 + 3) * HW_ + w];
        dst[w * (CIN / 4) + c4] = v0 | (v1 << 8) | (v2 << 16) | (v3 << 24);
    }
}

// ---------------- repack w: int32 [co][c][kh][kw] -> int8 [tap][co][c] ----------------
__global__ __launch_bounds__(256) void repack_w(const int* __restrict__ w32,
                                                char* __restrict__ wp) {
    int i = blockIdx.x * 256 + threadIdx.x;   // dword index < 73728
    int tap = i >> 13;
    int r   = i & 8191;
    int co  = r >> 5;
    int c4  = r & 31;
    const int* s = w32 + (co * CIN + c4 * 4) * 9 + tap;
    int v0 = s[0]  & 0xff;
    int v1 = s[9]  & 0xff;
    int v2 = s[18] & 0xff;
    int v3 = s[27] & 0xff;
    ((int*)wp)[i] = v0 | (v1 << 8) | (v2 << 16) | (v3 << 24);
}

// ---------------- main: implicit GEMM, BM=256 BN=64, wave tile 64x64 ----------------
// grid (M/256, COUT/64), 4 waves; B in LDS (6+3 taps, XOR-swizzled); A prefetched
// 1 tap ahead into ping-pong register buffers (explicit software pipeline).
__global__ __launch_bounds__(256, 2) void conv_mfma(const char* __restrict__ xp,
                                                    const char* __restrict__ wp,
                                                    const int*  __restrict__ bias,
                                                    const float* __restrict__ wsc,
                                                    int* __restrict__ out) {
    __shared__ char Bs[6 * 8192];                 // 48 KiB
    const int tid  = threadIdx.x;
    const int wave = tid >> 6, lane = tid & 63;
    const int l31 = lane & 31, lh = lane >> 5;
    const int m_base = blockIdx.x << 8;
    const int co0    = blockIdx.y << 6;

    const char* aptr[2];
    int tb[2];
#pragma unroll
    for (int mf = 0; mf < 2; ++mf) {
        tb[mf] = m_base + wave * 64 + mf * 32;    // multiple of 32; 3136%32==0 -> same n
        int row = tb[mf] + l31;
        int n  = row / SP_;
        int sp = row - n * SP_;
        int ho = sp / HW_;
        int wo = sp - ho * HW_;
        aptr[mf] = xp + (((size_t)(n * HP + ho) * HP + wo) << 7) + (lh << 4);
    }

    const char* wpb = wp + co0 * CIN;

    int16v acc[2][2] = {};

    // stage nt taps into slabs from Bs[0]; linear dest, inverse-swizzled source
    auto stageB = [&](int t0, int nt) {
        for (int i = wave; i < nt * 8; i += 4) {
            int p = (i << 10) + (lane << 4);              // linear LDS byte
            int q = p ^ (((p >> 7) & 7) << 4);            // swizzled source offset
            const char* src = wpb + (t0 + (p >> 13)) * (COUT * CIN) + (q & 8191);
            __builtin_amdgcn_global_load_lds(
                (const __attribute__((address_space(1))) void*)src,
                (__attribute__((address_space(3))) void*)&Bs[i << 10], 16, 0, 0);
        }
    };

    // load A fragments for one tap into a named register buffer
    auto aload = [&](int4v a[2][4], int tap) {
        int kh = tap / 3, kw = tap - kh * 3;
        int aoff = (kh * HP + kw) << 7;
#pragma unroll
        for (int kc = 0; kc < 4; ++kc) {
            a[0][kc] = *(const int4v*)(aptr[0] + aoff + kc * 32);
            a[1][kc] = *(const int4v*)(aptr[1] + aoff + kc * 32);
        }
    };

    // ds_read B for one slab + 16 MFMAs on the given A buffer
    auto ctap = [&](const int4v a[2][4], int slab) {
        int bbase = slab << 13;
        int sw = (l31 & 7) << 4;
        int4v b0[4], b1[4];
#pragma unroll
        for (int kc = 0; kc < 4; ++kc) {
            int koff = kc * 32 + (lh << 4);
            b0[kc] = *(const int4v*)&Bs[(bbase + (l31 << 7) + koff) ^ sw];
            b1[kc] = *(const int4v*)&Bs[(bbase + ((l31 + 32) << 7) + koff) ^ sw];
        }
#pragma unroll
        for (int kc = 0; kc < 4; ++kc) {
            acc[0][0] = __builtin_amdgcn_mfma_i32_32x32x32_i8(a[0][kc], b0[kc], acc[0][0], 0, 0, 0);
            acc[1][0] = __builtin_amdgcn_mfma_i32_32x32x32_i8(a[1][kc], b0[kc], acc[1][0], 0, 0, 0);
            acc[0][1] = __builtin_amdgcn_mfma_i32_32x32x32_i8(a[0][kc], b1[kc], acc[0][1], 0, 0, 0);
            acc[1][1] = __builtin_amdgcn_mfma_i32_32x32x32_i8(a[1][kc], b1[kc], acc[1][1], 0, 0, 0);
        }
    };

    int4v aA[2][4], aB[2][4];

    stageB(0, 6);                 // taps 0-5 -> slabs 0-5
    aload(aA, 0);                 // overlaps the stage drain
    __syncthreads();              // slabs 0-5 ready

    aload(aB, 1); ctap(aA, 0);    // tap0
    aload(aA, 2); ctap(aB, 1);    // tap1
    aload(aB, 3); ctap(aA, 2);    // tap2
    __syncthreads();              // all waves done reading slabs 0-2
    stageB(6, 3);                 // taps 6-8 -> slabs 0-2 (async, overlaps compute)
    aload(aA, 4); ctap(aB, 3);    // tap3
    aload(aB, 5); ctap(aA, 4);    // tap4
    aload(aA, 6); ctap(aB, 5);    // tap5
    __syncthreads();              // drains vmcnt -> slabs 0-2 hold taps 6-8
    aload(aB, 7); ctap(aA, 0);    // tap6
    aload(aA, 8); ctap(aB, 1);    // tap7
    ctap(aA, 2);                  // tap8

    // epilogue: C/D row = (r&3) + 8*(r>>2) + 4*lh; 4 consecutive sp -> dwordx4
#pragma unroll
    for (int mf = 0; mf < 2; ++mf) {
        int nu  = tb[mf] / SP_;
        int sp0 = tb[mf] - nu * SP_;
#pragma unroll
        for (int nf = 0; nf < 2; ++nf) {
            int co = co0 + nf * 32 + l31;
            float s = (0.02f * wsc[co]) / 0.1f;
            int bs = bias[co];
            int* ob = out + ((size_t)(nu * COUT + co)) * SP_ + sp0 + (lh << 2);
#pragma unroll
            for (int g = 0; g < 4; ++g) {
                int4v qv;
#pragma unroll
                for (int r = 0; r < 4; ++r) {
                    float v = (float)(acc[mf][nf][g * 4 + r] + bs) * s;
                    int q = (int)rintf(v);
                    qv[r] = q < -128 ? -128 : (q > 127 ? 127 : q);
                }
                *(int4v*)(ob + g * 8) = qv;
            }
        }
    }
}

extern "C" void kernel_launch(void* const* d_in, const int* in_sizes, int n_in,
                              void* d_out, int out_size, void* d_ws, size_t ws_size,
                              hipStream_t stream) {
    const int*   x32  = (const int*)d_in[0];
    const int*   w32  = (const int*)d_in[1];
    const int*   bias = (const int*)d_in[2];
    const float* wsc  = (const float*)d_in[3];

    char* xp = (char*)d_ws;
    char* wp = xp + XP_BYTES;

    hipMemsetAsync(xp, 0, XP_BYTES, stream);                       // zero halo (zp = 0)
    repack_x<<<dim3(N_ * HW_), 256, 0, stream>>>(x32, xp);
    repack_w<<<dim3(WP_BYTES / 4 / 256), 256, 0, stream>>>(w32, wp);
    conv_mfma<<<dim3(M_ / 256, COUT / 64), 256, 0, stream>>>(xp, wp, bias, wsc,
                                                             (int*)d_out);
}

// Round 6
// 76.497 us; speedup vs baseline: 2.5932x; 1.4563x over previous
//
#include <hip/hip_runtime.h>

#define N_      32
#define CIN     128
#define HW_     56
#define COUT    256
#define HP      58                    // padded spatial
#define SP_     (HW_*HW_)             // 3136
#define M_      (N_*SP_)              // 100352
// xp layout: [n][hp(58)][chunk16(8)][wp(58)][16B]  -> 7424 B per (n,hp) row
#define ROWB    7424
#define CHB     928                   // 58*16: bytes per chunk-plane
#define XP_BYTES (N_*HP*ROWB)         // 13,778,944
#define WP_BYTES (9*COUT*CIN)         // 294,912

typedef int int4v  __attribute__((ext_vector_type(4)));
typedef int int16v __attribute__((ext_vector_type(16)));

// ---- repack x: int32 NCHW -> int8 [n][hp][chunk][wp][16B], halo zero-filled ----
__global__ __launch_bounds__(256) void repack_x(const int* __restrict__ x32,
                                                char* __restrict__ xp) {
    __shared__ char s8[CIN * HW_];                    // [c][w] 7168 B
    int b = blockIdx.x;                               // b = n*58 + hp
    int n = b / HP;
    int hp = b - n * HP;
    int h = hp - 1;                                   // source h
    bool live = (h >= 0) && (h < HW_);
    if (live) {
        const int* src = x32 + ((size_t)(n * CIN)) * SP_ + h * HW_;
        for (int i = threadIdx.x; i < CIN * HW_; i += 256) {
            int c = i / HW_, w = i - c * HW_;
            s8[i] = (char)src[c * SP_ + w];
        }
    }
    __syncthreads();
    int* dst = (int*)(xp + (size_t)b * ROWB);
    for (int i = threadIdx.x; i < 8 * 232; i += 256) {   // 1856 dwords per row
        int chunk = i / 232, r = i - chunk * 232;
        int wp = r >> 2, sub = r & 3;
        int w = wp - 1;
        int v = 0;
        if (live && w >= 0 && w < HW_) {
            int c0 = chunk * 16 + sub * 4;
            int v0 = (unsigned char)s8[(c0 + 0) * HW_ + w];
            int v1 = (unsigned char)s8[(c0 + 1) * HW_ + w];
            int v2 = (unsigned char)s8[(c0 + 2) * HW_ + w];
            int v3 = (unsigned char)s8[(c0 + 3) * HW_ + w];
            v = v0 | (v1 << 8) | (v2 << 16) | (v3 << 24);
        }
        dst[i] = v;
    }
}

// ---------------- repack w: int32 [co][c][kh][kw] -> int8 [tap][co][c] ----------------
__global__ __launch_bounds__(256) void repack_w(const int* __restrict__ w32,
                                                char* __restrict__ wp) {
    int i = blockIdx.x * 256 + threadIdx.x;   // dword index < 73728
    int tap = i >> 13;
    int r   = i & 8191;
    int co  = r >> 5;
    int c4  = r & 31;
    const int* s = w32 + (co * CIN + c4 * 4) * 9 + tap;
    int v0 = s[0]  & 0xff;
    int v1 = s[9]  & 0xff;
    int v2 = s[18] & 0xff;
    int v3 = s[27] & 0xff;
    ((int*)wp)[i] = v0 | (v1 << 8) | (v2 << 16) | (v3 << 24);
}

// ---------------- main: implicit GEMM, BM=256 BN=64, wave tile 64x64 ----------------
// A loads are now contiguous 512-B half-wave segments (chunk-transposed xp);
// B in LDS (6+3 taps, XOR-swizzled); A prefetched 1 tap ahead (ping-pong regs).
__global__ __launch_bounds__(256, 2) void conv_mfma(const char* __restrict__ xp,
                                                    const char* __restrict__ wp,
                                                    const int*  __restrict__ bias,
                                                    const float* __restrict__ wsc,
                                                    int* __restrict__ out) {
    __shared__ char Bs[6 * 8192];                 // 48 KiB
    const int tid  = threadIdx.x;
    const int wave = tid >> 6, lane = tid & 63;
    const int l31 = lane & 31, lh = lane >> 5;
    const int m_base = blockIdx.x << 8;
    const int co0    = blockIdx.y << 6;

    const char* aptrT[2];
    int tb[2];
#pragma unroll
    for (int mf = 0; mf < 2; ++mf) {
        tb[mf] = m_base + wave * 64 + mf * 32;    // multiple of 32; 3136%32==0 -> same n
        int row = tb[mf] + l31;
        int n  = row / SP_;
        int sp = row - n * SP_;
        int ho = sp / HW_;
        int wo = sp - ho * HW_;
        // base at (n, ho, chunk=lh, wo); tap adds kh*ROWB + kw*16; kc adds 2*CHB
        aptrT[mf] = xp + (size_t)(n * HP + ho) * ROWB + lh * CHB + wo * 16;
    }

    const char* wpb = wp + co0 * CIN;

    int16v acc[2][2] = {};

    // stage nt taps into slabs from Bs[0]; linear dest, inverse-swizzled source
    auto stageB = [&](int t0, int nt) {
        for (int i = wave; i < nt * 8; i += 4) {
            int p = (i << 10) + (lane << 4);              // linear LDS byte
            int q = p ^ (((p >> 7) & 7) << 4);            // swizzled source offset
            const char* src = wpb + (t0 + (p >> 13)) * (COUT * CIN) + (q & 8191);
            __builtin_amdgcn_global_load_lds(
                (const __attribute__((address_space(1))) void*)src,
                (__attribute__((address_space(3))) void*)&Bs[i << 10], 16, 0, 0);
        }
    };

    // load A fragments for one tap into a named register buffer
    auto aload = [&](int4v a[2][4], int tap) {
        int kh = tap / 3, kw = tap - kh * 3;
        int aoff = kh * ROWB + kw * 16;
#pragma unroll
        for (int kc = 0; kc < 4; ++kc) {
            a[0][kc] = *(const int4v*)(aptrT[0] + aoff + kc * (2 * CHB));
            a[1][kc] = *(const int4v*)(aptrT[1] + aoff + kc * (2 * CHB));
        }
    };

    // ds_read B for one slab + 16 MFMAs on the given A buffer
    auto ctap = [&](const int4v a[2][4], int slab) {
        int bbase = slab << 13;
        int sw = (l31 & 7) << 4;
        int4v b0[4], b1[4];
#pragma unroll
        for (int kc = 0; kc < 4; ++kc) {
            int koff = kc * 32 + (lh << 4);
            b0[kc] = *(const int4v*)&Bs[(bbase + (l31 << 7) + koff) ^ sw];
            b1[kc] = *(const int4v*)&Bs[(bbase + ((l31 + 32) << 7) + koff) ^ sw];
        }
#pragma unroll
        for (int kc = 0; kc < 4; ++kc) {
            acc[0][0] = __builtin_amdgcn_mfma_i32_32x32x32_i8(a[0][kc], b0[kc], acc[0][0], 0, 0, 0);
            acc[1][0] = __builtin_amdgcn_mfma_i32_32x32x32_i8(a[1][kc], b0[kc], acc[1][0], 0, 0, 0);
            acc[0][1] = __builtin_amdgcn_mfma_i32_32x32x32_i8(a[0][kc], b1[kc], acc[0][1], 0, 0, 0);
            acc[1][1] = __builtin_amdgcn_mfma_i32_32x32x32_i8(a[1][kc], b1[kc], acc[1][1], 0, 0, 0);
        }
    };

    int4v aA[2][4], aB[2][4];

    stageB(0, 6);                 // taps 0-5 -> slabs 0-5
    aload(aA, 0);                 // overlaps the stage drain
    __syncthreads();              // slabs 0-5 ready

    aload(aB, 1); ctap(aA, 0);    // tap0
    aload(aA, 2); ctap(aB, 1);    // tap1
    aload(aB, 3); ctap(aA, 2);    // tap2
    __syncthreads();              // all waves done reading slabs 0-2
    stageB(6, 3);                 // taps 6-8 -> slabs 0-2 (async, overlaps compute)
    aload(aA, 4); ctap(aB, 3);    // tap3
    aload(aB, 5); ctap(aA, 4);    // tap4
    aload(aA, 6); ctap(aB, 5);    // tap5
    __syncthreads();              // drains vmcnt -> slabs 0-2 hold taps 6-8
    aload(aB, 7); ctap(aA, 0);    // tap6
    aload(aA, 8); ctap(aB, 1);    // tap7
    ctap(aA, 2);                  // tap8

    // epilogue: C/D row = (r&3) + 8*(r>>2) + 4*lh; 4 consecutive sp -> dwordx4
#pragma unroll
    for (int mf = 0; mf < 2; ++mf) {
        int nu  = tb[mf] / SP_;
        int sp0 = tb[mf] - nu * SP_;
#pragma unroll
        for (int nf = 0; nf < 2; ++nf) {
            int co = co0 + nf * 32 + l31;
            float s = (0.02f * wsc[co]) / 0.1f;
            int bs = bias[co];
            int* ob = out + ((size_t)(nu * COUT + co)) * SP_ + sp0 + (lh << 2);
#pragma unroll
            for (int g = 0; g < 4; ++g) {
                int4v qv;
#pragma unroll
                for (int r = 0; r < 4; ++r) {
                    float v = (float)(acc[mf][nf][g * 4 + r] + bs) * s;
                    int q = (int)rintf(v);
                    qv[r] = q < -128 ? -128 : (q > 127 ? 127 : q);
                }
                *(int4v*)(ob + g * 8) = qv;
            }
        }
    }
}

extern "C" void kernel_launch(void* const* d_in, const int* in_sizes, int n_in,
                              void* d_out, int out_size, void* d_ws, size_t ws_size,
                              hipStream_t stream) {
    const int*   x32  = (const int*)d_in[0];
    const int*   w32  = (const int*)d_in[1];
    const int*   bias = (const int*)d_in[2];
    const float* wsc  = (const float*)d_in[3];

    char* xp = (char*)d_ws;
    char* wp = xp + XP_BYTES;

    repack_x<<<dim3(N_ * HP), 256, 0, stream>>>(x32, xp);   // halo zeroed in-kernel
    repack_w<<<dim3(WP_BYTES / 4 / 256), 256, 0, stream>>>(w32, wp);
    conv_mfma<<<dim3(M_ / 256, COUT / 64), 256, 0, stream>>>(xp, wp, bias, wsc,
                                                             (int*)d_out);
}